// Round 1
// baseline (533.588 us; speedup 1.0000x reference)
//
#include <hip/hip_runtime.h>
#include <hip/hip_cooperative_groups.h>
#include <math.h>

namespace cg = cooperative_groups;

// Round 12: single-dispatch fused pipeline.
// Round-11 evidence: 8 small dispatches, total useful HBM traffic ~50 MB (~8 us
// at achieved BW) but 139.6 us wall -> dispatch-boundary bound. This version:
//   - ONE cooperative kernel (512 blocks x 256 thr, 2 blocks/CU co-resident),
//     7 grid.sync()s replace all kernel boundaries + the memset dispatch.
//   - Replica counters interleaved per bucket: count[b*4+r] (one uint4 line).
//     offArr/countTot/seq arrays deleted; replica prefix + bucket total are
//     recomputed from one 16B L2 read; atomic ticket stays in a register.
//   - Bucket scan stored as ascending exclusive prefix E[b];
//     start = n - E[b] - cnt, end = n - E[b]  (suffix derived, scan is natural).
// Tie-break (key desc, idx asc) identical to round 11 == jax.lax.top_k order.

#define BSHIFT 12
#define NBUCK (1 << 19)          // 524288 buckets (key>>12 of positive floats)
#define NREP 4                   // interleaved replicas per bucket
#define GRID 512
#define BLK 256
#define TOT (GRID * BLK)         // 131072 threads; N=262144 -> 2 elements/thread
#define BPB (NBUCK / GRID)       // 1024 buckets per block in scan phase
#define BPT (BPB / BLK)          // 4 buckets per thread

__global__ void __launch_bounds__(BLK, 2)
k_fused(const float2* __restrict__ yt0, const float* __restrict__ yp0,
        const float* __restrict__ yp1, const int* __restrict__ Hj,
        const float* __restrict__ lv, int n, int m,
        unsigned* __restrict__ count, unsigned* __restrict__ E,
        unsigned* __restrict__ bTot, uint2* __restrict__ skey2,
        unsigned* __restrict__ sidx, float* __restrict__ preS,
        float* __restrict__ seTot, float* __restrict__ xh,
        double* __restrict__ accum, float* __restrict__ out)
{
  cg::grid_group grid = cg::this_grid();
  const int t = threadIdx.x;
  const int g = blockIdx.x;
  const int gtid = g * BLK + t;

  __shared__ unsigned su[BLK];
  __shared__ float    sf[BLK];
  __shared__ float    pb[GRID];   // inclusive prefix of seTot (512 chunks)
  __shared__ double   sd[BLK];
  __shared__ float    wt[4];

  // ---------------- phase 0: zero count + accum ----------------
  {
    uint4 z; z.x = 0u; z.y = 0u; z.z = 0u; z.w = 0u;
    uint4* cp = (uint4*)count;
    #pragma unroll
    for (int k = 0; k < (NBUCK * NREP / 4) / TOT; ++k)   // 4 x uint4 per thread
      cp[(size_t)k * TOT + gtid] = z;
    if (gtid == 0) *accum = 0.0;
  }
  grid.sync();   // S1

  // ---------------- phase 1: histogram (ticket kept in register) ----------
  const int r = g & (NREP - 1);
  unsigned keyR[2]; float seR[2]; unsigned seqR[2]; unsigned evR[2];
  #pragma unroll
  for (int el = 0; el < 2; ++el) {
    int i = gtid + el * TOT;
    keyR[el] = 0u; seR[el] = 0.f; seqR[el] = 0u; evR[el] = 0u;
    if (i < n) {
      float2 te = yt0[i];
      unsigned key = __float_as_uint(te.x);
      keyR[el] = key;
      evR[el] = (te.y != 0.f) ? 0x80000000u : 0u;
      seR[el] = expf(yp0[i]);
      unsigned b = key >> BSHIFT;
      seqR[el] = atomicAdd(&count[(size_t)b * NREP + r], 1u);
    }
  }
  grid.sync();   // S2

  // ---------------- phase 2a: blocked bucket totals + in-block prefix -----
  unsigned incl[BPT]; unsigned thrBase; 
  {
    unsigned run = 0u;
    #pragma unroll
    for (int k = 0; k < BPT; ++k) {
      int b = g * BPB + t * BPT + k;
      uint4 c = ((const uint4*)count)[b];
      run += c.x + c.y + c.z + c.w;
      incl[k] = run;
    }
    su[t] = run;
    __syncthreads();
    for (int off = 1; off < BLK; off <<= 1) {     // inclusive Hillis-Steele
      unsigned v = (t >= off) ? su[t - off] : 0u;
      __syncthreads();
      su[t] += v;
      __syncthreads();
    }
    thrBase = (t > 0) ? su[t - 1] : 0u;           // exclusive base for thread
    if (t == BLK - 1) bTot[g] = su[t];
  }
  grid.sync();   // S3

  // ---------------- phase 2b: block base + write E (ascending excl prefix) -
  {
    unsigned part = 0u;
    for (int j = t; j < g; j += BLK) part += bTot[j];
    su[t] = part;
    __syncthreads();
    for (int s = 128; s > 0; s >>= 1) { if (t < s) su[t] += su[t + s]; __syncthreads(); }
    unsigned bBase = su[0];
    __syncthreads();
    unsigned e0 = bBase + thrBase;
    uint4 ev4;
    ev4.x = e0;
    ev4.y = e0 + incl[0];
    ev4.z = e0 + incl[1];
    ev4.w = e0 + incl[2];
    ((uint4*)E)[g * (BPB / 4) + t] = ev4;
  }
  grid.sync();   // S4

  // ---------------- phase 3: scatter (regs from phase 1) ------------------
  #pragma unroll
  for (int el = 0; el < 2; ++el) {
    int i = gtid + el * TOT;
    if (i < n) {
      unsigned key = keyR[el];
      unsigned b = key >> BSHIFT;
      uint4 c = ((const uint4*)count)[b];
      unsigned cnt = c.x + c.y + c.z + c.w;
      unsigned offr = 0u;
      if (r > 0) offr += c.x;
      if (r > 1) offr += c.y;
      if (r > 2) offr += c.z;
      unsigned start = (unsigned)n - E[b] - cnt;   // elems in higher buckets
      unsigned pos = start + offr + seqR[el];
      uint2 v; v.x = key; v.y = __float_as_uint(seR[el]);
      skey2[pos] = v;
      sidx[pos] = (unsigned)i | evR[el];
    }
  }
  grid.sync();   // S5

  // ---------------- phase 4: in-chunk inclusive scan of se (chunk=512) ----
  {
    int base = g * (2 * BLK);
    int p0 = base + 2 * t, p1 = p0 + 1;
    float e0 = (p0 < n) ? __uint_as_float(skey2[p0].y) : 0.f;
    float e1 = (p1 < n) ? __uint_as_float(skey2[p1].y) : 0.f;
    float pair = e0 + e1;
    sf[t] = pair;
    __syncthreads();
    for (int off = 1; off < BLK; off <<= 1) {
      float v = (t >= off) ? sf[t - off] : 0.f;
      __syncthreads();
      sf[t] += v;
      __syncthreads();
    }
    float ex = sf[t] - pair;                  // exclusive before this pair
    if (p0 < n) preS[p0] = ex + e0;
    if (p1 < n) preS[p1] = ex + e0 + e1;
    if (t == BLK - 1) seTot[g] = sf[t];
  }
  grid.sync();   // S6

  // ---------------- phase 5: main (rank + denom + xh scatter) -------------
  {
    // inclusive prefix of the 512 chunk totals into LDS pb[]
    float a0 = seTot[2 * t];
    float a1 = seTot[2 * t + 1];
    float pair = a0 + a1;
    sf[t] = pair;
    __syncthreads();
    for (int off = 1; off < BLK; off <<= 1) {
      float v = (t >= off) ? sf[t - off] : 0.f;
      __syncthreads();
      sf[t] += v;
      __syncthreads();
    }
    pb[2 * t]     = sf[t] - a1;
    pb[2 * t + 1] = sf[t];
    __syncthreads();

    double contrib = 0.0;
    #pragma unroll
    for (int el = 0; el < 2; ++el) {
      int p = gtid + el * TOT;
      if (p >= n) continue;
      uint2 kv = skey2[p];
      unsigned key = kv.x;
      float e = __uint_as_float(kv.y);
      unsigned sidv = sidx[p];
      unsigned idx = sidv & 0x7FFFFFFFu;
      bool evb = (sidv >> 31) != 0u;
      unsigned b = key >> BSHIFT;
      uint4 c4 = ((const uint4*)count)[b];
      unsigned cnt = c4.x + c4.y + c4.z + c4.w;
      unsigned end = (unsigned)n - E[b];
      unsigned start = end - cnt;
      if (end > (unsigned)n) end = (unsigned)n;    // defensive clamps
      if (start > end) start = end;
      float wsum = 0.f;
      unsigned wcnt = 0u;
      unsigned q = start;
      while (q + 8 <= end) {                        // 8x batched MLP loads
        uint2 v[8];
        #pragma unroll
        for (int k = 0; k < 8; ++k) v[k] = skey2[q + k];
        #pragma unroll
        for (int k = 0; k < 8; ++k) {
          if (v[k].x > key) { wsum += __uint_as_float(v[k].y); wcnt++; }
          else if (v[k].x == key && (sidx[q + k] & 0x7FFFFFFFu) < idx) {
            wsum += __uint_as_float(v[k].y); wcnt++;
          }
        }
        q += 8;
      }
      for (; q < end; ++q) {
        uint2 v = skey2[q];
        if (v.x > key) { wsum += __uint_as_float(v.y); wcnt++; }
        else if (v.x == key && (sidx[q] & 0x7FFFFFFFu) < idx) {
          wsum += __uint_as_float(v.y); wcnt++;
        }
      }
      unsigned sb = start >> 9;                     // chunk = 512 elements
      float cross = ((sb > 0) ? pb[sb - 1] : 0.f)
                  + ((start & 511u) ? preS[start - 1] : 0.f);
      float denom = cross + wsum + e;
      int rank = (int)(start + wcnt);
      if (evb) contrib += (double)logf(denom / e);
      int lo = 0, hi = m;
      while (lo < hi) { int mid = (lo + hi) >> 1; if (Hj[mid] < rank) lo = mid + 1; else hi = mid; }
      if (lo < m && Hj[lo] == rank) {
        float xb1 = yp1[idx];
        for (int j = lo; j < m && Hj[j] == rank; ++j) xh[j] = xb1;
      }
    }
    sd[t] = contrib;
    __syncthreads();
    for (int s = 128; s > 0; s >>= 1) { if (t < s) sd[t] += sd[t + s]; __syncthreads(); }
    if (t == 0) atomicAdd(accum, sd[0]);
  }
  grid.sync();   // S7

  // ---------------- phase 6: cost2 + combine (block 0 only) ---------------
  if (g != 0) return;
  {
    int lane = t & 63;
    int w = t >> 6;
    double acc = 0.0;
    float carry = 0.f;
    int passes = (m + 2047) / 2048;      // 4 for m=8192 (256 thr x 8 elem)
    for (int pss = passes - 1; pss >= 0; --pss) {
      int base = pss * 2048 + t * 8;
      float x[8], eb[8];
      float c = 0.f;
      #pragma unroll
      for (int k = 0; k < 8; ++k) {
        int j = base + k;
        x[k] = (j < m) ? xh[j] : 0.f;
        eb[k] = (j < m) ? expf(-x[k]) : 0.f;
        c += eb[k];
      }
      float s = c;
      #pragma unroll
      for (int d = 1; d < 64; d <<= 1) {
        float o = __shfl_down(s, d, 64);
        if (lane + d < 64) s += o;
      }
      float wtot = __shfl(s, 0, 64);
      if (lane == 0) wt[w] = wtot;
      __syncthreads();
      float after = 0.f, ptot = 0.f;
      #pragma unroll
      for (int w2 = 0; w2 < 4; ++w2) { ptot += wt[w2]; if (w2 > w) after += wt[w2]; }
      float S = (s - c) + after + carry;
      #pragma unroll
      for (int k = 7; k >= 0; --k) {
        int j = base + k;
        S += eb[k];
        if (j < m) acc += (double)(expf(x[k]) * S);
      }
      __syncthreads();
      carry += ptot;
    }
    sd[t] = acc;
    __syncthreads();
    for (int s2 = 128; s2 > 0; s2 >>= 1) { if (t < s2) sd[t] += sd[t + s2]; __syncthreads(); }
    if (t == 0) {
      double T = (double)m * (double)(m + 1) * 0.5;
      double cost2 = T - sd[0];
      float lv0 = lv[0], lv1 = lv[1];
      float prec1 = fminf(expf(-lv1), 1.0f);
      double loss = *accum + (double)n * (double)lv0 + (double)prec1 * cost2 + (double)lv1;
      out[0] = (float)loss;
    }
  }
}

extern "C" void kernel_launch(void* const* d_in, const int* in_sizes, int n_in,
                              void* d_out, int out_size, void* d_ws, size_t ws_size,
                              hipStream_t stream) {
  (void)n_in; (void)out_size;
  const float2* yt0 = (const float2*)d_in[0];
  const float*  yp0 = (const float*)d_in[2];
  const float*  yp1 = (const float*)d_in[3];
  const int*    Hj  = (const int*)d_in[4];
  const float*  lv  = (const float*)d_in[5];
  int n = in_sizes[0] / 2;   // y_true0 is [N,2]
  int m = in_sizes[4];

  char* ws = (char*)d_ws;
  size_t off = 0;
  auto alloc = [&](size_t bytes) -> void* {
    void* p = ws + off;
    off += (bytes + 255) & ~(size_t)255;
    return p;
  };
  unsigned* count = (unsigned*)alloc((size_t)NBUCK * NREP * 4);  // 8 MB
  unsigned* E     = (unsigned*)alloc((size_t)NBUCK * 4);         // 2 MB
  unsigned* bTot  = (unsigned*)alloc((size_t)GRID * 4);
  uint2*    skey2 = (uint2*)alloc((size_t)n * 8);
  unsigned* sidx  = (unsigned*)alloc((size_t)n * 4);
  float*    preS  = (float*)alloc((size_t)n * 4);
  float*    seTot = (float*)alloc((size_t)GRID * 4);
  float*    xh    = (float*)alloc((size_t)m * 4);
  double*   accum = (double*)alloc(16);
  if (off > ws_size) return;   // workspace too small (should never happen)

  float* outp = (float*)d_out;
  void* args[] = { &yt0, &yp0, &yp1, &Hj, &lv, &n, &m,
                   &count, &E, &bTot, &skey2, &sidx, &preS, &seTot, &xh,
                   &accum, &outp };
  hipLaunchCooperativeKernel(k_fused, dim3(GRID), dim3(BLK), args, 0, stream);
}

// Round 2
// 178.355 us; speedup vs baseline: 2.9917x; 2.9917x over previous
//
#include <hip/hip_runtime.h>
#include <math.h>

// Round 13: fused pipeline with CUSTOM grid barrier (no cg::sync, no fences).
// Round-12 evidence: 7x cg::grid_group::sync() ~= 65us each (VALUBusy 1.4%,
// kernel 467us, work ~15us). ockl grid-sync pays per-block agent acq/rel
// fences (buffer_wbl2/buffer_inv on every L2) + sleep-backoff spin.
// This version:
//   - Barrier = 2-level monotonic arrival counters + generation flag, all
//     RELAXED agent-scope atomics, s_sleep(16) spin. No cache maintenance.
//   - Correctness without fences: every cross-barrier producer write uses a
//     relaxed AGENT-scope atomic store (sc1 -> bypasses non-coherent per-XCD
//     L2, lands at the coherent point). Consumers plain-load strictly
//     first-touch-after-write, so no stale L2 line can exist. 'count' is
//     touched only by device-scope atomics before its first plain read.
//     __syncthreads() at barrier entry drains each wave's vmcnt (m97).
//   - Zero phase replaced by one hipMemsetAsync (barrier state + count,
//     contiguous): 7 barriers -> 6.
//   - GRID=1024 (4 blocks/CU, launch_bounds(256,4)) for 2x latency hiding in
//     the gather-bound main phase; 1 element/thread.
// Phase math identical to round-12 (verified absmax==0).

#define BSHIFT 12
#define NBUCK (1 << 19)          // 524288 buckets (key>>12 of positive floats)
#define NREP 4                   // interleaved replicas per bucket
#define BLK 256
#define NC1 32                   // level-1 arrival counters

#define STORE_U32(p, v) __hip_atomic_store((p), (v), __ATOMIC_RELAXED, __HIP_MEMORY_SCOPE_AGENT)
#define STORE_F32(p, v) __hip_atomic_store((p), (v), __ATOMIC_RELAXED, __HIP_MEMORY_SCOPE_AGENT)
#define STORE_U64(p, v) __hip_atomic_store((unsigned long long*)(p), (v), __ATOMIC_RELAXED, __HIP_MEMORY_SCOPE_AGENT)

// bar layout (u32 indices): c1[i] at i*16 (i<32, 64B padded); c2 at 512;
// gen at 528. Monotonic targets: barrier gv complete when c1 hits gv*BPC,
// c2 hits gv*NC1. No resets -> no reset races; zeroed by host memset.
template <int GRID>
__device__ __forceinline__ void gbar(unsigned* bar, unsigned gv) {
  __syncthreads();   // drains each wave's vmcnt/lgkmcnt (compiler-inserted)
  if (threadIdx.x == 0) {
    constexpr unsigned BPC = GRID / NC1;
    unsigned a = __hip_atomic_fetch_add(bar + (blockIdx.x & (NC1 - 1)) * 16, 1u,
                                        __ATOMIC_RELAXED, __HIP_MEMORY_SCOPE_AGENT);
    if (a == gv * BPC - 1u) {
      unsigned b = __hip_atomic_fetch_add(bar + NC1 * 16, 1u,
                                          __ATOMIC_RELAXED, __HIP_MEMORY_SCOPE_AGENT);
      if (b == gv * NC1 - 1u)
        STORE_U32(bar + NC1 * 16 + 16, gv);
    }
    int guard = 0;
    while (__hip_atomic_load(bar + NC1 * 16 + 16, __ATOMIC_RELAXED,
                             __HIP_MEMORY_SCOPE_AGENT) < gv) {
      __builtin_amdgcn_s_sleep(16);
      if (++guard > 4000000) break;   // ~2s failsafe: never hang the queue
    }
  }
  __syncthreads();
}

template <int GRID>
__global__ void __launch_bounds__(BLK, 4)
k_fused(const float2* __restrict__ yt0, const float* __restrict__ yp0,
        const float* __restrict__ yp1, const int* __restrict__ Hj,
        const float* __restrict__ lv, int n, int m,
        unsigned* __restrict__ bar,
        unsigned* __restrict__ count, unsigned* __restrict__ E,
        unsigned* __restrict__ bTot, uint2* __restrict__ skey2,
        unsigned* __restrict__ sidx, float* __restrict__ preS,
        float* __restrict__ seTot, float* __restrict__ xh,
        double* __restrict__ accum, float* __restrict__ out)
{
  constexpr int TOT = GRID * BLK;
  constexpr int BPB = NBUCK / GRID;   // buckets per block in scan phase
  constexpr int BPT = BPB / BLK;      // buckets per thread (2 @GRID=1024)
  const int t = threadIdx.x;
  const int g = blockIdx.x;
  const int gtid = g * BLK + t;

  __shared__ unsigned su[BLK];
  __shared__ float    sf[BLK];
  __shared__ float    pb[512];        // prefix of 512 se-chunk totals
  __shared__ double   sd[BLK];
  __shared__ float    wt[4];

  // -------- phase 1: histogram (count pre-zeroed by host memset) ----------
  const int r = g & (NREP - 1);
  unsigned keyR[2]; float seR[2]; unsigned seqR[2]; unsigned evR[2];
  #pragma unroll
  for (int el = 0; el < 2; ++el) {
    int i = gtid + el * TOT;
    keyR[el] = 0u; seR[el] = 0.f; seqR[el] = 0u; evR[el] = 0u;
    if (i < n) {
      float2 te = yt0[i];
      unsigned key = __float_as_uint(te.x);
      keyR[el] = key;
      evR[el] = (te.y != 0.f) ? 0x80000000u : 0u;
      seR[el] = expf(yp0[i]);
      seqR[el] = atomicAdd(&count[(size_t)(key >> BSHIFT) * NREP + r], 1u);
    }
  }
  gbar<GRID>(bar, 1);

  // -------- phase 2a: bucket totals + in-block prefix; publish bTot -------
  unsigned incl[BPT]; unsigned thrBase;
  {
    unsigned run = 0u;
    #pragma unroll
    for (int k = 0; k < BPT; ++k) {
      int b = g * BPB + t * BPT + k;
      uint4 c = ((const uint4*)count)[b];
      run += c.x + c.y + c.z + c.w;
      incl[k] = run;
    }
    su[t] = run;
    __syncthreads();
    for (int off2 = 1; off2 < BLK; off2 <<= 1) {
      unsigned v = (t >= off2) ? su[t - off2] : 0u;
      __syncthreads();
      su[t] += v;
      __syncthreads();
    }
    thrBase = (t > 0) ? su[t - 1] : 0u;
    if (t == BLK - 1) STORE_U32(&bTot[g], su[t]);
  }
  gbar<GRID>(bar, 2);

  // -------- phase 2b: block base + write E (ascending excl prefix) --------
  {
    unsigned part = 0u;
    for (int j = t; j < g; j += BLK) part += bTot[j];
    su[t] = part;
    __syncthreads();
    for (int s = BLK / 2; s > 0; s >>= 1) { if (t < s) su[t] += su[t + s]; __syncthreads(); }
    unsigned bBase = su[0];
    __syncthreads();
    unsigned e0 = bBase + thrBase;
    int ebase = g * BPB + t * BPT;
    if constexpr (BPT == 2) {
      unsigned long long w = ((unsigned long long)(e0 + incl[0]) << 32) | e0;
      STORE_U64(&E[ebase], w);
    } else {
      unsigned long long w0 = ((unsigned long long)(e0 + incl[0]) << 32) | e0;
      unsigned long long w1 = ((unsigned long long)(e0 + incl[2]) << 32) | (e0 + incl[1]);
      STORE_U64(&E[ebase], w0);
      STORE_U64(&E[ebase + 2], w1);
    }
  }
  gbar<GRID>(bar, 3);

  // -------- phase 3: scatter (key/ev/exp(xbeta)/ticket from registers) ----
  #pragma unroll
  for (int el = 0; el < 2; ++el) {
    int i = gtid + el * TOT;
    if (i < n) {
      unsigned key = keyR[el];
      unsigned b = key >> BSHIFT;
      uint4 c = ((const uint4*)count)[b];
      unsigned cnt = c.x + c.y + c.z + c.w;
      unsigned offr = 0u;
      if (r > 0) offr += c.x;
      if (r > 1) offr += c.y;
      if (r > 2) offr += c.z;
      unsigned start = (unsigned)n - E[b] - cnt;   // elems in higher buckets
      unsigned pos = start + offr + seqR[el];
      unsigned long long v =
          ((unsigned long long)__float_as_uint(seR[el]) << 32) | key;
      STORE_U64(&skey2[pos], v);
      STORE_U32(&sidx[pos], (unsigned)i | evR[el]);
    }
  }
  gbar<GRID>(bar, 4);

  // -------- phase 4: se chunk scan (512-element chunks, blocks 0..511) ----
  if (g < 512) {
    int base = g * (2 * BLK);
    int p0 = base + 2 * t, p1 = p0 + 1;
    float e0 = (p0 < n) ? __uint_as_float(skey2[p0].y) : 0.f;
    float e1 = (p1 < n) ? __uint_as_float(skey2[p1].y) : 0.f;
    float pairv = e0 + e1;
    sf[t] = pairv;
    __syncthreads();
    for (int off2 = 1; off2 < BLK; off2 <<= 1) {
      float v = (t >= off2) ? sf[t - off2] : 0.f;
      __syncthreads();
      sf[t] += v;
      __syncthreads();
    }
    float ex = sf[t] - pairv;
    if (p0 < n) STORE_F32(&preS[p0], ex + e0);
    if (p1 < n) STORE_F32(&preS[p1], ex + e0 + e1);
    if (t == BLK - 1) STORE_F32(&seTot[g], sf[t]);
  }
  gbar<GRID>(bar, 5);

  // -------- phase 5: main (rank + denom + lossA + xh scatter) -------------
  {
    float a0 = seTot[2 * t];
    float a1 = seTot[2 * t + 1];
    float pairv = a0 + a1;
    sf[t] = pairv;
    __syncthreads();
    for (int off2 = 1; off2 < BLK; off2 <<= 1) {
      float v = (t >= off2) ? sf[t - off2] : 0.f;
      __syncthreads();
      sf[t] += v;
      __syncthreads();
    }
    pb[2 * t]     = sf[t] - a1;
    pb[2 * t + 1] = sf[t];
    __syncthreads();

    double contrib = 0.0;
    #pragma unroll
    for (int el = 0; el < 2; ++el) {
      int p = gtid + el * TOT;
      if (p >= n) continue;
      uint2 kv = skey2[p];
      unsigned key = kv.x;
      float e = __uint_as_float(kv.y);
      unsigned sidv = sidx[p];
      unsigned idx = sidv & 0x7FFFFFFFu;
      bool evb = (sidv >> 31) != 0u;
      unsigned b = key >> BSHIFT;
      uint4 c4 = ((const uint4*)count)[b];
      unsigned cnt = c4.x + c4.y + c4.z + c4.w;
      unsigned end = (unsigned)n - E[b];
      unsigned start = end - cnt;
      if (end > (unsigned)n) end = (unsigned)n;    // defensive clamps
      if (start > end) start = end;
      float wsum = 0.f;
      unsigned wcnt = 0u;
      unsigned q = start;
      while (q + 8 <= end) {                        // 8x batched MLP loads
        uint2 v[8];
        #pragma unroll
        for (int k = 0; k < 8; ++k) v[k] = skey2[q + k];
        #pragma unroll
        for (int k = 0; k < 8; ++k) {
          if (v[k].x > key) { wsum += __uint_as_float(v[k].y); wcnt++; }
          else if (v[k].x == key && (sidx[q + k] & 0x7FFFFFFFu) < idx) {
            wsum += __uint_as_float(v[k].y); wcnt++;
          }
        }
        q += 8;
      }
      for (; q < end; ++q) {
        uint2 v = skey2[q];
        if (v.x > key) { wsum += __uint_as_float(v.y); wcnt++; }
        else if (v.x == key && (sidx[q] & 0x7FFFFFFFu) < idx) {
          wsum += __uint_as_float(v.y); wcnt++;
        }
      }
      unsigned sb = start >> 9;                     // chunk = 512 elements
      float cross = ((sb > 0) ? pb[sb - 1] : 0.f)
                  + ((start & 511u) ? preS[start - 1] : 0.f);
      float denom = cross + wsum + e;
      int rank = (int)(start + wcnt);
      if (evb) contrib += (double)logf(denom / e);
      int lo = 0, hi = m;
      while (lo < hi) { int mid = (lo + hi) >> 1; if (Hj[mid] < rank) lo = mid + 1; else hi = mid; }
      if (lo < m && Hj[lo] == rank) {
        float xb1 = yp1[idx];
        for (int j = lo; j < m && Hj[j] == rank; ++j) STORE_F32(&xh[j], xb1);
      }
    }
    sd[t] = contrib;
    __syncthreads();
    for (int s = 128; s > 0; s >>= 1) { if (t < s) sd[t] += sd[t + s]; __syncthreads(); }
    if (t == 0) atomicAdd(accum, sd[0]);
  }
  gbar<GRID>(bar, 6);

  // -------- phase 6: cost2 + combine (block 0 only) -----------------------
  if (g != 0) return;
  {
    int lane = t & 63;
    int w = t >> 6;
    double acc = 0.0;
    float carry = 0.f;
    int passes = (m + 2047) / 2048;      // 4 for m=8192 (256 thr x 8 elem)
    for (int pss = passes - 1; pss >= 0; --pss) {
      int base = pss * 2048 + t * 8;
      float x[8], eb[8];
      float c = 0.f;
      #pragma unroll
      for (int k = 0; k < 8; ++k) {
        int j = base + k;
        x[k] = (j < m) ? xh[j] : 0.f;
        eb[k] = (j < m) ? expf(-x[k]) : 0.f;
        c += eb[k];
      }
      float s = c;
      #pragma unroll
      for (int d = 1; d < 64; d <<= 1) {
        float o = __shfl_down(s, d, 64);
        if (lane + d < 64) s += o;
      }
      float wtot = __shfl(s, 0, 64);
      if (lane == 0) wt[w] = wtot;
      __syncthreads();
      float after = 0.f, ptot = 0.f;
      #pragma unroll
      for (int w2 = 0; w2 < 4; ++w2) { ptot += wt[w2]; if (w2 > w) after += wt[w2]; }
      float S = (s - c) + after + carry;
      #pragma unroll
      for (int k = 7; k >= 0; --k) {
        int j = base + k;
        S += eb[k];
        if (j < m) acc += (double)(expf(x[k]) * S);
      }
      __syncthreads();
      carry += ptot;
    }
    sd[t] = acc;
    __syncthreads();
    for (int s2 = 128; s2 > 0; s2 >>= 1) { if (t < s2) sd[t] += sd[t + s2]; __syncthreads(); }
    if (t == 0) {
      double T = (double)m * (double)(m + 1) * 0.5;
      double cost2 = T - sd[0];
      float lv0 = lv[0], lv1 = lv[1];
      float prec1 = fminf(expf(-lv1), 1.0f);
      double loss = *accum + (double)n * (double)lv0 + (double)prec1 * cost2 + (double)lv1;
      out[0] = (float)loss;
    }
  }
}

extern "C" void kernel_launch(void* const* d_in, const int* in_sizes, int n_in,
                              void* d_out, int out_size, void* d_ws, size_t ws_size,
                              hipStream_t stream) {
  (void)n_in; (void)out_size;
  const float2* yt0 = (const float2*)d_in[0];
  const float*  yp0 = (const float*)d_in[2];
  const float*  yp1 = (const float*)d_in[3];
  const int*    Hj  = (const int*)d_in[4];
  const float*  lv  = (const float*)d_in[5];
  int n = in_sizes[0] / 2;   // y_true0 is [N,2]
  int m = in_sizes[4];

  char* ws = (char*)d_ws;
  unsigned* bar   = (unsigned*)ws;            // 4 KB barrier state (zeroed)
  double*   accum = (double*)(ws + 2560);     // inside zeroed region
  size_t off = 4096;
  auto alloc = [&](size_t bytes) -> void* {
    void* p = ws + off;
    off += (bytes + 255) & ~(size_t)255;
    return p;
  };
  unsigned* count = (unsigned*)alloc((size_t)NBUCK * NREP * 4);  // 8 MB (zeroed)
  unsigned* E     = (unsigned*)alloc((size_t)NBUCK * 4);         // 2 MB
  unsigned* bTot  = (unsigned*)alloc(1024 * 4);
  uint2*    skey2 = (uint2*)alloc((size_t)n * 8);
  unsigned* sidx  = (unsigned*)alloc((size_t)n * 4);
  float*    preS  = (float*)alloc((size_t)n * 4);
  float*    seTot = (float*)alloc(1024 * 4);
  float*    xh    = (float*)alloc((size_t)m * 4);
  if (off > ws_size) return;

  // one contiguous fill: barrier state + count
  hipMemsetAsync(ws, 0, 4096 + (size_t)NBUCK * NREP * 4, stream);

  float* outp = (float*)d_out;
  void* args[] = { &yt0, &yp0, &yp1, &Hj, &lv, &n, &m, &bar,
                   &count, &E, &bTot, &skey2, &sidx, &preS, &seTot, &xh,
                   &accum, &outp };

  // GRID=1024 (4 blocks/CU); static one-time co-residency check with 512
  // fallback (both instantiated).
  static int gridChoice = 0;
  if (gridChoice == 0) {
    int nb = 0;
    hipError_t e1 = hipOccupancyMaxActiveBlocksPerMultiprocessor(&nb, k_fused<1024>, BLK, 0);
    int dev = 0; hipGetDevice(&dev);
    hipDeviceProp_t prop;
    hipError_t e2 = hipGetDeviceProperties(&prop, dev);
    gridChoice = (e1 == hipSuccess && e2 == hipSuccess &&
                  nb * prop.multiProcessorCount >= 1024) ? 1024 : 512;
  }
  if (gridChoice == 1024)
    hipLaunchCooperativeKernel(k_fused<1024>, dim3(1024), dim3(BLK), args, 0, stream);
  else
    hipLaunchCooperativeKernel(k_fused<512>, dim3(512), dim3(BLK), args, 0, stream);
}

// Round 3
// 138.079 us; speedup vs baseline: 3.8644x; 1.2917x over previous
//
#include <hip/hip_runtime.h>
#include <math.h>

// Round 14: fused pipeline, REGULAR launch (no cooperative), broadcast-release
// grid barrier.
// Round-13 evidence: kernel 88.5us but wall 178us -> ~88us launch gap from
// hipLaunchCooperativeKernel (not graph-capturable / heavyweight validation).
// Co-residency is already guaranteed structurally: __launch_bounds__(256,4),
// 28 VGPR, 6.6KB LDS -> 4 blocks/CU, grid 1024 = 4*256 CUs. Spin guard is the
// failsafe. So: plain <<<>>> launch, graph-capturable.
// Barrier v2: 32 padded generation copies, last arriver broadcasts, each
// leader polls copy[blockIdx&31] (32 pollers/line, no single-line hotspot),
// s_sleep(8). All phase math byte-identical to round 13 (absmax==0.0).

#define BSHIFT 12
#define NBUCK (1 << 19)          // 524288 buckets (key>>12 of positive floats)
#define NREP 4                   // interleaved replicas per bucket
#define BLK 256
#define NC1 32                   // level-1 arrival counters / release copies

#define STORE_U32(p, v) __hip_atomic_store((p), (v), __ATOMIC_RELAXED, __HIP_MEMORY_SCOPE_AGENT)
#define STORE_F32(p, v) __hip_atomic_store((p), (v), __ATOMIC_RELAXED, __HIP_MEMORY_SCOPE_AGENT)
#define STORE_U64(p, v) __hip_atomic_store((unsigned long long*)(p), (v), __ATOMIC_RELAXED, __HIP_MEMORY_SCOPE_AGENT)

// bar u32 layout: c1[i] @ i*16 (i<32, 64B padded); c2 @ 512;
// genCopy[i] @ 544 + i*16. Monotonic (no resets); zeroed by host memset.
template <int GRID>
__device__ __forceinline__ void gbar(unsigned* bar, unsigned gv) {
  __syncthreads();   // all waves of this block done; drains vm/lgkm counts
  if (threadIdx.x == 0) {
    constexpr unsigned BPC = GRID / NC1;
    const unsigned grp = blockIdx.x & (NC1 - 1);
    unsigned a = __hip_atomic_fetch_add(bar + grp * 16, 1u,
                                        __ATOMIC_RELAXED, __HIP_MEMORY_SCOPE_AGENT);
    if (a == gv * BPC - 1u) {
      unsigned b = __hip_atomic_fetch_add(bar + 512, 1u,
                                          __ATOMIC_RELAXED, __HIP_MEMORY_SCOPE_AGENT);
      if (b == gv * NC1 - 1u) {
        #pragma unroll
        for (int i = 0; i < NC1; ++i)
          STORE_U32(bar + 544 + i * 16, gv);   // broadcast release
      }
    }
    int guard = 0;
    while (__hip_atomic_load(bar + 544 + grp * 16, __ATOMIC_RELAXED,
                             __HIP_MEMORY_SCOPE_AGENT) < gv) {
      __builtin_amdgcn_s_sleep(8);
      if (++guard > 8000000) break;   // failsafe: never hang the queue
    }
  }
  __syncthreads();
}

template <int GRID>
__global__ void __launch_bounds__(BLK, 4)
k_fused(const float2* __restrict__ yt0, const float* __restrict__ yp0,
        const float* __restrict__ yp1, const int* __restrict__ Hj,
        const float* __restrict__ lv, int n, int m,
        unsigned* __restrict__ bar,
        unsigned* __restrict__ count, unsigned* __restrict__ E,
        unsigned* __restrict__ bTot, uint2* __restrict__ skey2,
        unsigned* __restrict__ sidx, float* __restrict__ preS,
        float* __restrict__ seTot, float* __restrict__ xh,
        double* __restrict__ accum, float* __restrict__ out)
{
  constexpr int TOT = GRID * BLK;
  constexpr int BPB = NBUCK / GRID;   // buckets per block in scan phase
  constexpr int BPT = BPB / BLK;      // buckets per thread (2 @GRID=1024)
  const int t = threadIdx.x;
  const int g = blockIdx.x;
  const int gtid = g * BLK + t;

  __shared__ unsigned su[BLK];
  __shared__ float    sf[BLK];
  __shared__ float    pb[512];        // prefix of 512 se-chunk totals
  __shared__ double   sd[BLK];
  __shared__ float    wt[4];

  // -------- phase 1: histogram (count pre-zeroed by host memset) ----------
  const int r = g & (NREP - 1);
  unsigned keyR[2]; float seR[2]; unsigned seqR[2]; unsigned evR[2];
  #pragma unroll
  for (int el = 0; el < 2; ++el) {
    int i = gtid + el * TOT;
    keyR[el] = 0u; seR[el] = 0.f; seqR[el] = 0u; evR[el] = 0u;
    if (i < n) {
      float2 te = yt0[i];
      unsigned key = __float_as_uint(te.x);
      keyR[el] = key;
      evR[el] = (te.y != 0.f) ? 0x80000000u : 0u;
      seR[el] = expf(yp0[i]);
      seqR[el] = atomicAdd(&count[(size_t)(key >> BSHIFT) * NREP + r], 1u);
    }
  }
  gbar<GRID>(bar, 1);

  // -------- phase 2a: bucket totals + in-block prefix; publish bTot -------
  unsigned incl[BPT]; unsigned thrBase;
  {
    unsigned run = 0u;
    #pragma unroll
    for (int k = 0; k < BPT; ++k) {
      int b = g * BPB + t * BPT + k;
      uint4 c = ((const uint4*)count)[b];
      run += c.x + c.y + c.z + c.w;
      incl[k] = run;
    }
    su[t] = run;
    __syncthreads();
    for (int off2 = 1; off2 < BLK; off2 <<= 1) {
      unsigned v = (t >= off2) ? su[t - off2] : 0u;
      __syncthreads();
      su[t] += v;
      __syncthreads();
    }
    thrBase = (t > 0) ? su[t - 1] : 0u;
    if (t == BLK - 1) STORE_U32(&bTot[g], su[t]);
  }
  gbar<GRID>(bar, 2);

  // -------- phase 2b: block base + write E (ascending excl prefix) --------
  {
    unsigned part = 0u;
    for (int j = t; j < g; j += BLK) part += bTot[j];
    su[t] = part;
    __syncthreads();
    for (int s = BLK / 2; s > 0; s >>= 1) { if (t < s) su[t] += su[t + s]; __syncthreads(); }
    unsigned bBase = su[0];
    __syncthreads();
    unsigned e0 = bBase + thrBase;
    int ebase = g * BPB + t * BPT;
    if constexpr (BPT == 2) {
      unsigned long long w = ((unsigned long long)(e0 + incl[0]) << 32) | e0;
      STORE_U64(&E[ebase], w);
    } else {
      unsigned long long w0 = ((unsigned long long)(e0 + incl[0]) << 32) | e0;
      unsigned long long w1 = ((unsigned long long)(e0 + incl[2]) << 32) | (e0 + incl[1]);
      STORE_U64(&E[ebase], w0);
      STORE_U64(&E[ebase + 2], w1);
    }
  }
  gbar<GRID>(bar, 3);

  // -------- phase 3: scatter (key/ev/exp(xbeta)/ticket from registers) ----
  #pragma unroll
  for (int el = 0; el < 2; ++el) {
    int i = gtid + el * TOT;
    if (i < n) {
      unsigned key = keyR[el];
      unsigned b = key >> BSHIFT;
      uint4 c = ((const uint4*)count)[b];
      unsigned cnt = c.x + c.y + c.z + c.w;
      unsigned offr = 0u;
      if (r > 0) offr += c.x;
      if (r > 1) offr += c.y;
      if (r > 2) offr += c.z;
      unsigned start = (unsigned)n - E[b] - cnt;   // elems in higher buckets
      unsigned pos = start + offr + seqR[el];
      unsigned long long v =
          ((unsigned long long)__float_as_uint(seR[el]) << 32) | key;
      STORE_U64(&skey2[pos], v);
      STORE_U32(&sidx[pos], (unsigned)i | evR[el]);
    }
  }
  gbar<GRID>(bar, 4);

  // -------- phase 4: se chunk scan (512-element chunks, blocks 0..511) ----
  if (g < 512) {
    int base = g * (2 * BLK);
    int p0 = base + 2 * t, p1 = p0 + 1;
    float e0 = (p0 < n) ? __uint_as_float(skey2[p0].y) : 0.f;
    float e1 = (p1 < n) ? __uint_as_float(skey2[p1].y) : 0.f;
    float pairv = e0 + e1;
    sf[t] = pairv;
    __syncthreads();
    for (int off2 = 1; off2 < BLK; off2 <<= 1) {
      float v = (t >= off2) ? sf[t - off2] : 0.f;
      __syncthreads();
      sf[t] += v;
      __syncthreads();
    }
    float ex = sf[t] - pairv;
    if (p0 < n) STORE_F32(&preS[p0], ex + e0);
    if (p1 < n) STORE_F32(&preS[p1], ex + e0 + e1);
    if (t == BLK - 1) STORE_F32(&seTot[g], sf[t]);
  }
  gbar<GRID>(bar, 5);

  // -------- phase 5: main (rank + denom + lossA + xh scatter) -------------
  {
    float a0 = seTot[2 * t];
    float a1 = seTot[2 * t + 1];
    float pairv = a0 + a1;
    sf[t] = pairv;
    __syncthreads();
    for (int off2 = 1; off2 < BLK; off2 <<= 1) {
      float v = (t >= off2) ? sf[t - off2] : 0.f;
      __syncthreads();
      sf[t] += v;
      __syncthreads();
    }
    pb[2 * t]     = sf[t] - a1;
    pb[2 * t + 1] = sf[t];
    __syncthreads();

    double contrib = 0.0;
    #pragma unroll
    for (int el = 0; el < 2; ++el) {
      int p = gtid + el * TOT;
      if (p >= n) continue;
      uint2 kv = skey2[p];
      unsigned key = kv.x;
      float e = __uint_as_float(kv.y);
      unsigned sidv = sidx[p];
      unsigned idx = sidv & 0x7FFFFFFFu;
      bool evb = (sidv >> 31) != 0u;
      unsigned b = key >> BSHIFT;
      uint4 c4 = ((const uint4*)count)[b];
      unsigned cnt = c4.x + c4.y + c4.z + c4.w;
      unsigned end = (unsigned)n - E[b];
      unsigned start = end - cnt;
      if (end > (unsigned)n) end = (unsigned)n;    // defensive clamps
      if (start > end) start = end;
      float wsum = 0.f;
      unsigned wcnt = 0u;
      unsigned q = start;
      while (q + 8 <= end) {                        // 8x batched MLP loads
        uint2 v[8];
        #pragma unroll
        for (int k = 0; k < 8; ++k) v[k] = skey2[q + k];
        #pragma unroll
        for (int k = 0; k < 8; ++k) {
          if (v[k].x > key) { wsum += __uint_as_float(v[k].y); wcnt++; }
          else if (v[k].x == key && (sidx[q + k] & 0x7FFFFFFFu) < idx) {
            wsum += __uint_as_float(v[k].y); wcnt++;
          }
        }
        q += 8;
      }
      for (; q < end; ++q) {
        uint2 v = skey2[q];
        if (v.x > key) { wsum += __uint_as_float(v.y); wcnt++; }
        else if (v.x == key && (sidx[q] & 0x7FFFFFFFu) < idx) {
          wsum += __uint_as_float(v.y); wcnt++;
        }
      }
      unsigned sb = start >> 9;                     // chunk = 512 elements
      float cross = ((sb > 0) ? pb[sb - 1] : 0.f)
                  + ((start & 511u) ? preS[start - 1] : 0.f);
      float denom = cross + wsum + e;
      int rank = (int)(start + wcnt);
      if (evb) contrib += (double)logf(denom / e);
      int lo = 0, hi = m;
      while (lo < hi) { int mid = (lo + hi) >> 1; if (Hj[mid] < rank) lo = mid + 1; else hi = mid; }
      if (lo < m && Hj[lo] == rank) {
        float xb1 = yp1[idx];
        for (int j = lo; j < m && Hj[j] == rank; ++j) STORE_F32(&xh[j], xb1);
      }
    }
    sd[t] = contrib;
    __syncthreads();
    for (int s = 128; s > 0; s >>= 1) { if (t < s) sd[t] += sd[t + s]; __syncthreads(); }
    if (t == 0) atomicAdd(accum, sd[0]);
  }
  gbar<GRID>(bar, 6);

  // -------- phase 6: cost2 + combine (block 0 only) -----------------------
  if (g != 0) return;
  {
    int lane = t & 63;
    int w = t >> 6;
    double acc = 0.0;
    float carry = 0.f;
    int passes = (m + 2047) / 2048;      // 4 for m=8192 (256 thr x 8 elem)
    for (int pss = passes - 1; pss >= 0; --pss) {
      int base = pss * 2048 + t * 8;
      float x[8], eb[8];
      float c = 0.f;
      #pragma unroll
      for (int k = 0; k < 8; ++k) {
        int j = base + k;
        x[k] = (j < m) ? xh[j] : 0.f;
        eb[k] = (j < m) ? expf(-x[k]) : 0.f;
        c += eb[k];
      }
      float s = c;
      #pragma unroll
      for (int d = 1; d < 64; d <<= 1) {
        float o = __shfl_down(s, d, 64);
        if (lane + d < 64) s += o;
      }
      float wtot = __shfl(s, 0, 64);
      if (lane == 0) wt[w] = wtot;
      __syncthreads();
      float after = 0.f, ptot = 0.f;
      #pragma unroll
      for (int w2 = 0; w2 < 4; ++w2) { ptot += wt[w2]; if (w2 > w) after += wt[w2]; }
      float S = (s - c) + after + carry;
      #pragma unroll
      for (int k = 7; k >= 0; --k) {
        int j = base + k;
        S += eb[k];
        if (j < m) acc += (double)(expf(x[k]) * S);
      }
      __syncthreads();
      carry += ptot;
    }
    sd[t] = acc;
    __syncthreads();
    for (int s2 = 128; s2 > 0; s2 >>= 1) { if (t < s2) sd[t] += sd[t + s2]; __syncthreads(); }
    if (t == 0) {
      double T = (double)m * (double)(m + 1) * 0.5;
      double cost2 = T - sd[0];
      float lv0 = lv[0], lv1 = lv[1];
      float prec1 = fminf(expf(-lv1), 1.0f);
      double loss = *accum + (double)n * (double)lv0 + (double)prec1 * cost2 + (double)lv1;
      out[0] = (float)loss;
    }
  }
}

extern "C" void kernel_launch(void* const* d_in, const int* in_sizes, int n_in,
                              void* d_out, int out_size, void* d_ws, size_t ws_size,
                              hipStream_t stream) {
  (void)n_in; (void)out_size;
  const float2* yt0 = (const float2*)d_in[0];
  const float*  yp0 = (const float*)d_in[2];
  const float*  yp1 = (const float*)d_in[3];
  const int*    Hj  = (const int*)d_in[4];
  const float*  lv  = (const float*)d_in[5];
  int n = in_sizes[0] / 2;   // y_true0 is [N,2]
  int m = in_sizes[4];

  char* ws = (char*)d_ws;
  unsigned* bar   = (unsigned*)ws;            // 8 KB barrier state (zeroed)
  double*   accum = (double*)(ws + 6144);     // own line inside zeroed region
  size_t off = 8192;
  auto alloc = [&](size_t bytes) -> void* {
    void* p = ws + off;
    off += (bytes + 255) & ~(size_t)255;
    return p;
  };
  unsigned* count = (unsigned*)alloc((size_t)NBUCK * NREP * 4);  // 8 MB (zeroed)
  unsigned* E     = (unsigned*)alloc((size_t)NBUCK * 4);         // 2 MB
  unsigned* bTot  = (unsigned*)alloc(1024 * 4);
  uint2*    skey2 = (uint2*)alloc((size_t)n * 8);
  unsigned* sidx  = (unsigned*)alloc((size_t)n * 4);
  float*    preS  = (float*)alloc((size_t)n * 4);
  float*    seTot = (float*)alloc(1024 * 4);
  float*    xh    = (float*)alloc((size_t)m * 4);
  if (off > ws_size) return;

  // one contiguous fill: barrier state + count
  hipMemsetAsync(ws, 0, 8192 + (size_t)NBUCK * NREP * 4, stream);

  // Regular launch (graph-capturable). Co-residency by construction:
  // __launch_bounds__(256,4), 28 VGPR, 6.6KB LDS -> 4 blocks/CU; grid 1024
  // = 4 * 256 CUs. Spin guard in gbar is the failsafe.
  k_fused<1024><<<dim3(1024), dim3(BLK), 0, stream>>>(
      yt0, yp0, yp1, Hj, lv, n, m, bar, count, E, bTot, skey2, sidx,
      preS, seTot, xh, accum, (float*)d_out);
}